// Round 13
// baseline (56.201 us; speedup 1.0000x reference)
//
#include <hip/hip_runtime.h>
#include <math.h>

#define L 4096
#define C2 32
#define CTOT 64
#define BB 4
#define NG 4
#define NSAMP 2048
#define TPB 256
#define ROWSPB 32            // one 32-row tile per block; 4 waves = 4 sample-quarters
#define AOFF 196608          // B-ws: 64 tiles x 3072 B; A-ws follows
#define WS_B 196608
#define WS_A (196608 + 6291456)   // + 2048 rowtiles x 2 kh x 32 col x 48 B

typedef _Float16 half8 __attribute__((ext_vector_type(8)));
typedef float f32x16 __attribute__((ext_vector_type(16)));

__device__ __forceinline__ void split3(float x, _Float16& h, _Float16& m, _Float16& l) {
    h = (_Float16)x; float r1 = x - (float)h;
    m = (_Float16)r1; float r2 = r1 - (float)m;
    l = (_Float16)r2;
}

// ---- prep: blocks 0..7 presplit B samples; blocks 8..263 precompute A-frags ----
// B tile = n>>5 (3072 B): level*1024 + kh*512 + col*16; kh0 = s^2, kh1 = s.
// A frag (rowtile rtg, kh, col): 48 B = {h,m,l} half8 over g; row = rtg*32+col,
// k = kh*8+g; kh0 = ca = 0.5*(1-iv), kh1 = cb = mu*iv.
__global__ __launch_bounds__(256) void prep_kernel(
    const float* __restrict__ z, const float* __restrict__ prior,
    char* __restrict__ ws)
{
    const int blk = blockIdx.x, tid = threadIdx.x;
    if (blk < 8) {
        int n = blk * 256 + tid;
        const float4* p4 = (const float4*)prior;
        float4 u = p4[2 * n], v = p4[2 * n + 1];
        float s[8] = {u.x, u.y, u.z, u.w, v.x, v.y, v.z, v.w};
        half8 qh, qm, ql, vh, vm, vl;
        #pragma unroll
        for (int g = 0; g < 8; ++g) {
            _Float16 hh, mm, ll;
            split3(s[g] * s[g], hh, mm, ll);
            qh[g] = hh; qm[g] = mm; ql[g] = ll;
            split3(s[g], hh, mm, ll);
            vh[g] = hh; vm[g] = mm; vl[g] = ll;
        }
        char* tb = ws + (size_t)(n >> 5) * 3072 + (size_t)(n & 31) * 16;
        *(half8*)(tb + 0)    = qh;
        *(half8*)(tb + 512)  = vh;
        *(half8*)(tb + 1024) = qm;
        *(half8*)(tb + 1536) = vm;
        *(half8*)(tb + 2048) = ql;
        *(half8*)(tb + 2560) = vl;
    } else {
        int r = (blk - 8) * 256 + tid;            // global row 0..65535
        int rtg = r >> 5, col = r & 31;
        int b = r >> 14, pos = (r >> 2) & (L - 1), ns = r & 3;
        const float* zb = z + (size_t)b * CTOT * L + pos;
        half8 cah, cam, cal, cbh, cbm, cbl;
        #pragma unroll
        for (int g = 0; g < 8; ++g) {
            float mu = zb[(size_t)(g * NG + ns) * L];
            float lv = zb[(size_t)(C2 + g * NG + ns) * L];
            lv = fminf(fmaxf(lv, -30.f), 20.f);
            float iv = expf(-lv);
            _Float16 hh, mm, ll;
            split3(0.5f - 0.5f * iv, hh, mm, ll);
            cah[g] = hh; cam[g] = mm; cal[g] = ll;
            split3(mu * iv, hh, mm, ll);
            cbh[g] = hh; cbm[g] = mm; cbl[g] = ll;
        }
        char* b0 = ws + AOFF + (size_t)(((rtg * 2 + 0) * 32 + col)) * 48;
        *(half8*)(b0 + 0) = cah; *(half8*)(b0 + 16) = cam; *(half8*)(b0 + 32) = cal;
        char* b1 = ws + AOFF + (size_t)(((rtg * 2 + 1) * 32 + col)) * 48;
        *(half8*)(b1 + 0) = cbh; *(half8*)(b1 + 16) = cbm; *(half8*)(b1 + 32) = cbl;
    }
}

// ---- main: 32x32x16 f16 MFMA score+argmax (3-way split, 6 terms — numerics
// identical to R7..R12, absmax 0). Block = ONE 32-row tile; wave sh (0..3)
// scans 16 sample-tiles (512 samples) as 8 dual-chain iterations. 2048 blocks
// x 4 waves = 8192 waves = 8/SIMD nominal (VGPR=64 fits the 8-wave quantum).
// A/B frags from L2-resident ws; no main-loop barriers.
// D: col=lane&31, row=(reg&3)+8*(reg>>2)+4*(lane>>5) (HW-validated R8..R12).
__global__ __launch_bounds__(TPB) void gqreg_main(
    const float* __restrict__ z, const float* __restrict__ prior,
    float* __restrict__ out, const char* __restrict__ wsb, int bws, int aws)
{
    __shared__ float mbB[4][2][16];   // [sh][kh][j]
    __shared__ int   mbI[4][2][16];

    const int tid = threadIdx.x;
    const int lane = tid & 63;
    const int sh = tid >> 6;
    const int col = lane & 31;
    const int kh = lane >> 5;
    const float4* p4 = (const float4*)prior;
    const int rowbase = blockIdx.x * ROWSPB;

    // ---- A fragments: 3 x 16B loads from ws (or fallback compute) ----
    half8 ah, am, al;
    if (aws) {
        const char* ab = wsb + AOFF + (size_t)((blockIdx.x * 2 + kh) * 32 + col) * 48;
        ah = *(const half8*)(ab + 0);
        am = *(const half8*)(ab + 16);
        al = *(const half8*)(ab + 32);
    } else {
        int r = rowbase + col;
        int b = r >> 14, pos = (r >> 2) & (L - 1), ns = r & 3;
        const float* zb = z + (size_t)b * CTOT * L + pos;
        #pragma unroll
        for (int g = 0; g < 8; ++g) {
            float mu = zb[(size_t)(g * NG + ns) * L];
            float lv = zb[(size_t)(C2 + g * NG + ns) * L];
            lv = fminf(fmaxf(lv, -30.f), 20.f);
            float iv = expf(-lv);
            float x = kh ? (mu * iv) : (0.5f - 0.5f * iv);
            _Float16 xh, xm, xl;
            split3(x, xh, xm, xl);
            ah[g] = xh; am[g] = xm; al[g] = xl;
        }
    }

    float best[16];
    int bt[16];
    #pragma unroll
    for (int j = 0; j < 16; ++j) { best[j] = -INFINITY; bt[j] = 0; }
    const f32x16 z16 = {};

    if (bws) {
        const char* tb = wsb + (size_t)(sh * 16) * 3072 + (size_t)(kh * 512 + col * 16);
        #pragma unroll 2
        for (int t = 0; t < 8; ++t) {
            const int tt0 = sh * 16 + 2 * t, tt1 = tt0 + 1;
            const char* p0 = tb;
            const char* p1 = tb + 3072;
            tb += 6144;
            half8 B0h = *(const half8*)(p0 + 0);
            half8 B0m = *(const half8*)(p0 + 1024);
            half8 B0l = *(const half8*)(p0 + 2048);
            half8 B1h = *(const half8*)(p1 + 0);
            half8 B1m = *(const half8*)(p1 + 1024);
            half8 B1l = *(const half8*)(p1 + 2048);
            f32x16 a0, a1;
            a0 = __builtin_amdgcn_mfma_f32_32x32x16_f16(ah, B0h, z16, 0, 0, 0);
            a1 = __builtin_amdgcn_mfma_f32_32x32x16_f16(ah, B1h, z16, 0, 0, 0);
            a0 = __builtin_amdgcn_mfma_f32_32x32x16_f16(ah, B0m, a0, 0, 0, 0);
            a1 = __builtin_amdgcn_mfma_f32_32x32x16_f16(ah, B1m, a1, 0, 0, 0);
            a0 = __builtin_amdgcn_mfma_f32_32x32x16_f16(am, B0h, a0, 0, 0, 0);
            a1 = __builtin_amdgcn_mfma_f32_32x32x16_f16(am, B1h, a1, 0, 0, 0);
            a0 = __builtin_amdgcn_mfma_f32_32x32x16_f16(am, B0m, a0, 0, 0, 0);
            a1 = __builtin_amdgcn_mfma_f32_32x32x16_f16(am, B1m, a1, 0, 0, 0);
            a0 = __builtin_amdgcn_mfma_f32_32x32x16_f16(ah, B0l, a0, 0, 0, 0);
            a1 = __builtin_amdgcn_mfma_f32_32x32x16_f16(ah, B1l, a1, 0, 0, 0);
            a0 = __builtin_amdgcn_mfma_f32_32x32x16_f16(al, B0h, a0, 0, 0, 0);
            a1 = __builtin_amdgcn_mfma_f32_32x32x16_f16(al, B1h, a1, 0, 0, 0);
            #pragma unroll
            for (int j = 0; j < 16; ++j) {
                bool g0 = a0[j] > best[j];
                best[j] = g0 ? a0[j] : best[j];
                bt[j]   = g0 ? tt0 : bt[j];
                bool g1 = a1[j] > best[j];
                best[j] = g1 ? a1[j] : best[j];
                bt[j]   = g1 ? tt1 : bt[j];
            }
        }
    } else {
        // fallback: split B in-VALU per tile
        #pragma unroll 2
        for (int t = 0; t < 16; ++t) {
            const int tt = sh * 16 + t;
            int n = tt * 32 + col;
            float4 u = p4[2 * n], v = p4[2 * n + 1];
            float sv[8] = {u.x, u.y, u.z, u.w, v.x, v.y, v.z, v.w};
            half8 Bh, Bm, Bl;
            #pragma unroll
            for (int g = 0; g < 8; ++g) {
                float x = kh ? sv[g] : sv[g] * sv[g];
                _Float16 hh, mm, ll;
                split3(x, hh, mm, ll);
                Bh[g] = hh; Bm[g] = mm; Bl[g] = ll;
            }
            f32x16 acc;
            acc = __builtin_amdgcn_mfma_f32_32x32x16_f16(ah, Bh, z16, 0, 0, 0);
            acc = __builtin_amdgcn_mfma_f32_32x32x16_f16(ah, Bm, acc, 0, 0, 0);
            acc = __builtin_amdgcn_mfma_f32_32x32x16_f16(am, Bh, acc, 0, 0, 0);
            acc = __builtin_amdgcn_mfma_f32_32x32x16_f16(am, Bm, acc, 0, 0, 0);
            acc = __builtin_amdgcn_mfma_f32_32x32x16_f16(ah, Bl, acc, 0, 0, 0);
            acc = __builtin_amdgcn_mfma_f32_32x32x16_f16(al, Bh, acc, 0, 0, 0);
            #pragma unroll
            for (int j = 0; j < 16; ++j) {
                bool gt = acc[j] > best[j];
                best[j] = gt ? acc[j] : best[j];
                bt[j]   = gt ? tt : bt[j];
            }
        }
    }

    // ---- recover n; cross-col reduce within kh half (tie -> lowest n) ----
    int bn[16];
    #pragma unroll
    for (int j = 0; j < 16; ++j) bn[j] = bt[j] * 32 + col;
    #pragma unroll
    for (int j = 0; j < 16; ++j) {
        #pragma unroll
        for (int m = 1; m < 32; m <<= 1) {
            float os = __shfl_xor(best[j], m, 64);
            int oi = __shfl_xor(bn[j], m, 64);
            if (os > best[j] || (os == best[j] && oi < bn[j])) {
                best[j] = os; bn[j] = oi;
            }
        }
    }

    // ---- post per-wave results (2 active lanes/wave -> no conflicts) ----
    if (col == 0) {
        #pragma unroll
        for (int j = 0; j < 16; ++j) {
            mbB[sh][kh][j] = best[j];
            mbI[sh][kh][j] = bn[j];
        }
    }
    __syncthreads();

    // ---- merge sample-quarters (sh ascending = n ascending; strict > keeps
    //      lowest) and write the 32 rows, one per lane of wave 0 ----
    if (tid < 32) {
        int rr = tid;
        int kh_o = (rr >> 2) & 1;
        int j_o = (rr & 3) | ((rr >> 3) << 2);
        float bv = mbB[0][kh_o][j_o];
        int n = mbI[0][kh_o][j_o];
        #pragma unroll
        for (int s = 1; s < 4; ++s) {
            float ob = mbB[s][kh_o][j_o];
            int oi = mbI[s][kh_o][j_o];
            if (ob > bv) { bv = ob; n = oi; }
        }
        int r = rowbase + rr;
        int b = r >> 14, pos = (r >> 2) & (L - 1), ns = r & 3;
        out[(size_t)BB * C2 * L + ((size_t)b * NG + ns) * L + pos] = (float)n;
        float4 uu = p4[2 * n], vv = p4[2 * n + 1];
        float sv[8] = {uu.x, uu.y, uu.z, uu.w, vv.x, vv.y, vv.z, vv.w};
        #pragma unroll
        for (int g = 0; g < 8; ++g) {
            out[((size_t)b * C2 + g * NG + ns) * L + pos] = sv[g];
        }
    }
}

extern "C" void kernel_launch(void* const* d_in, const int* in_sizes, int n_in,
                              void* d_out, int out_size, void* d_ws, size_t ws_size,
                              hipStream_t stream) {
    const float* z = (const float*)d_in[0];
    const float* prior = (const float*)d_in[1];
    float* out = (float*)d_out;
    char* ws = (char*)d_ws;
    int bws = (ws_size >= (size_t)WS_B) ? 1 : 0;
    int aws = (ws_size >= (size_t)WS_A) ? 1 : 0;

    if (bws) {
        int nprep = 8 + (aws ? 256 : 0);
        hipLaunchKernelGGL(prep_kernel, dim3(nprep), dim3(256), 0, stream,
                           z, prior, ws);
    }
    hipLaunchKernelGGL(gqreg_main, dim3((BB * L * NG) / ROWSPB), dim3(TPB), 0, stream,
                       z, prior, out, (const char*)ws, bws, aws);
}

// Round 14
// 46.020 us; speedup vs baseline: 1.2212x; 1.2212x over previous
//
#include <hip/hip_runtime.h>
#include <math.h>

#define L 4096
#define C2 32
#define CTOT 64
#define BB 4
#define NG 4
#define NSAMP 2048
#define TPB 256
#define ROWSPB 64            // per block: 2 row-tiles x 32 rows (rt), 2 sample-halves (sh)
#define AOFF 196608          // B-ws: 64 tiles x 3072 B; A-ws follows
#define WS_B 196608
#define WS_A (196608 + 6291456)   // + 2048 rowtiles x 2 kh x 32 col x 48 B

typedef _Float16 half8 __attribute__((ext_vector_type(8)));
typedef float f32x16 __attribute__((ext_vector_type(16)));

__device__ __forceinline__ void split3(float x, _Float16& h, _Float16& m, _Float16& l) {
    h = (_Float16)x; float r1 = x - (float)h;
    m = (_Float16)r1; float r2 = r1 - (float)m;
    l = (_Float16)r2;
}

// ---- prep: blocks 0..7 presplit B samples; blocks 8..263 precompute A-frags ----
__global__ __launch_bounds__(256) void prep_kernel(
    const float* __restrict__ z, const float* __restrict__ prior,
    char* __restrict__ ws)
{
    const int blk = blockIdx.x, tid = threadIdx.x;
    if (blk < 8) {
        int n = blk * 256 + tid;
        const float4* p4 = (const float4*)prior;
        float4 u = p4[2 * n], v = p4[2 * n + 1];
        float s[8] = {u.x, u.y, u.z, u.w, v.x, v.y, v.z, v.w};
        half8 qh, qm, ql, vh, vm, vl;
        #pragma unroll
        for (int g = 0; g < 8; ++g) {
            _Float16 hh, mm, ll;
            split3(s[g] * s[g], hh, mm, ll);
            qh[g] = hh; qm[g] = mm; ql[g] = ll;
            split3(s[g], hh, mm, ll);
            vh[g] = hh; vm[g] = mm; vl[g] = ll;
        }
        char* tb = ws + (size_t)(n >> 5) * 3072 + (size_t)(n & 31) * 16;
        *(half8*)(tb + 0)    = qh;
        *(half8*)(tb + 512)  = vh;
        *(half8*)(tb + 1024) = qm;
        *(half8*)(tb + 1536) = vm;
        *(half8*)(tb + 2048) = ql;
        *(half8*)(tb + 2560) = vl;
    } else {
        int r = (blk - 8) * 256 + tid;            // global row 0..65535
        int rtg = r >> 5, col = r & 31;
        int b = r >> 14, pos = (r >> 2) & (L - 1), ns = r & 3;
        const float* zb = z + (size_t)b * CTOT * L + pos;
        half8 cah, cam, cal, cbh, cbm, cbl;
        #pragma unroll
        for (int g = 0; g < 8; ++g) {
            float mu = zb[(size_t)(g * NG + ns) * L];
            float lv = zb[(size_t)(C2 + g * NG + ns) * L];
            lv = fminf(fmaxf(lv, -30.f), 20.f);
            float iv = expf(-lv);
            _Float16 hh, mm, ll;
            split3(0.5f - 0.5f * iv, hh, mm, ll);
            cah[g] = hh; cam[g] = mm; cal[g] = ll;
            split3(mu * iv, hh, mm, ll);
            cbh[g] = hh; cbm[g] = mm; cbl[g] = ll;
        }
        char* b0 = ws + AOFF + (size_t)(((rtg * 2 + 0) * 32 + col)) * 48;
        *(half8*)(b0 + 0) = cah; *(half8*)(b0 + 16) = cam; *(half8*)(b0 + 32) = cal;
        char* b1 = ws + AOFF + (size_t)(((rtg * 2 + 1) * 32 + col)) * 48;
        *(half8*)(b1 + 0) = cbh; *(half8*)(b1 + 16) = cbm; *(half8*)(b1 + 32) = cbl;
    }
}

__device__ __forceinline__ void argmax16(const f32x16& acc, int tt,
                                         float* best, int* bt) {
    #pragma unroll
    for (int j = 0; j < 16; ++j) {
        bool gt = acc[j] > best[j];
        best[j] = gt ? acc[j] : best[j];
        bt[j]   = gt ? tt : bt[j];
    }
}

// ---- main: R12 structure (2 rt x 2 sh waves, 1024 blocks) + deferred-argmax
// software pipeline + VGPR-resident accumulators (__launch_bounds__(256,4)
// -> 128-reg budget, no AGPR round-trip). Numerics identical to R7..R13
// (3-way f16 split, 6 MFMA terms; absmax 0 every round).
// D: col=lane&31, row=(reg&3)+8*(reg>>2)+4*(lane>>5) (HW-validated).
__global__ __launch_bounds__(TPB, 4) void gqreg_main(
    const float* __restrict__ z, const float* __restrict__ prior,
    float* __restrict__ out, const char* __restrict__ wsb, int bws, int aws)
{
    __shared__ float mbB[2][2][2][16];   // [rt][sh][kh][j]
    __shared__ int   mbI[2][2][2][16];

    const int tid = threadIdx.x;
    const int lane = tid & 63;
    const int w = tid >> 6;
    const int rt = w >> 1;
    const int sh = w & 1;
    const int col = lane & 31;
    const int kh = lane >> 5;
    const float4* p4 = (const float4*)prior;
    const int rowbase = blockIdx.x * ROWSPB + rt * 32;

    // ---- A fragments: 3 x 16B loads from ws (or fallback compute) ----
    half8 ah, am, al;
    if (aws) {
        int rtg = blockIdx.x * 2 + rt;
        const char* ab = wsb + AOFF + (size_t)((rtg * 2 + kh) * 32 + col) * 48;
        ah = *(const half8*)(ab + 0);
        am = *(const half8*)(ab + 16);
        al = *(const half8*)(ab + 32);
    } else {
        int r = rowbase + col;
        int b = r >> 14, pos = (r >> 2) & (L - 1), ns = r & 3;
        const float* zb = z + (size_t)b * CTOT * L + pos;
        #pragma unroll
        for (int g = 0; g < 8; ++g) {
            float mu = zb[(size_t)(g * NG + ns) * L];
            float lv = zb[(size_t)(C2 + g * NG + ns) * L];
            lv = fminf(fmaxf(lv, -30.f), 20.f);
            float iv = expf(-lv);
            float x = kh ? (mu * iv) : (0.5f - 0.5f * iv);
            _Float16 xh, xm, xl;
            split3(x, xh, xm, xl);
            ah[g] = xh; am[g] = xm; al[g] = xl;
        }
    }

    float best[16];
    int bt[16];
    #pragma unroll
    for (int j = 0; j < 16; ++j) { best[j] = -INFINITY; bt[j] = 0; }
    const f32x16 z16 = {};

#define CHAIN(dst, Bh_, Bm_, Bl_)                                              \
    do {                                                                       \
        __builtin_amdgcn_s_setprio(1);                                         \
        dst = __builtin_amdgcn_mfma_f32_32x32x16_f16(ah, Bh_, z16, 0, 0, 0);   \
        dst = __builtin_amdgcn_mfma_f32_32x32x16_f16(ah, Bm_, dst, 0, 0, 0);   \
        dst = __builtin_amdgcn_mfma_f32_32x32x16_f16(am, Bh_, dst, 0, 0, 0);   \
        dst = __builtin_amdgcn_mfma_f32_32x32x16_f16(am, Bm_, dst, 0, 0, 0);   \
        dst = __builtin_amdgcn_mfma_f32_32x32x16_f16(ah, Bl_, dst, 0, 0, 0);   \
        dst = __builtin_amdgcn_mfma_f32_32x32x16_f16(al, Bh_, dst, 0, 0, 0);   \
        __builtin_amdgcn_s_setprio(0);                                         \
    } while (0)

    if (bws) {
        const char* base = wsb + (size_t)(sh * 32) * 3072 + (size_t)(kh * 512 + col * 16);
        const int tbase = sh * 32;
        half8 Xh, Xm, Xl, Yh, Ym, Yl;
        f32x16 aA, aB;
        // prologue: tile 0 -> X
        Xh = *(const half8*)(base + 0);
        Xm = *(const half8*)(base + 1024);
        Xl = *(const half8*)(base + 2048);
        // steady state per i: LOAD Y(2i+1); argmax(aB, 2i-1); CHAIN(aA, X);
        //                     LOAD X(2i+2); CHAIN(aB, Y); argmax(aA, 2i)
        #pragma unroll
        for (int i = 0; i < 16; ++i) {
            {
                const char* q = base + (size_t)(2 * i + 1) * 3072;
                Yh = *(const half8*)(q + 0);
                Ym = *(const half8*)(q + 1024);
                Yl = *(const half8*)(q + 2048);
            }
            if (i > 0) argmax16(aB, tbase + 2 * i - 1, best, bt);
            CHAIN(aA, Xh, Xm, Xl);
            if (i + 1 < 16) {
                const char* q = base + (size_t)(2 * i + 2) * 3072;
                Xh = *(const half8*)(q + 0);
                Xm = *(const half8*)(q + 1024);
                Xl = *(const half8*)(q + 2048);
            }
            CHAIN(aB, Yh, Ym, Yl);
            argmax16(aA, tbase + 2 * i, best, bt);
        }
        argmax16(aB, tbase + 31, best, bt);
    } else {
        // fallback: split B in-VALU per tile (R12-validated)
        #pragma unroll 2
        for (int t = 0; t < 32; ++t) {
            const int tt = sh * 32 + t;
            int n = tt * 32 + col;
            float4 u = p4[2 * n], v = p4[2 * n + 1];
            float sv[8] = {u.x, u.y, u.z, u.w, v.x, v.y, v.z, v.w};
            half8 Bh, Bm, Bl;
            #pragma unroll
            for (int g = 0; g < 8; ++g) {
                float x = kh ? sv[g] : sv[g] * sv[g];
                _Float16 hh, mm, ll;
                split3(x, hh, mm, ll);
                Bh[g] = hh; Bm[g] = mm; Bl[g] = ll;
            }
            f32x16 acc;
            CHAIN(acc, Bh, Bm, Bl);
            argmax16(acc, tt, best, bt);
        }
    }
#undef CHAIN

    // ---- recover n; cross-col reduce within kh half (tie -> lowest n) ----
    int bn[16];
    #pragma unroll
    for (int j = 0; j < 16; ++j) bn[j] = bt[j] * 32 + col;
    #pragma unroll
    for (int j = 0; j < 16; ++j) {
        #pragma unroll
        for (int m = 1; m < 32; m <<= 1) {
            float os = __shfl_xor(best[j], m, 64);
            int oi = __shfl_xor(bn[j], m, 64);
            if (os > best[j] || (os == best[j] && oi < bn[j])) {
                best[j] = os; bn[j] = oi;
            }
        }
    }

    // ---- post per-wave results (2 active lanes/wave -> no conflicts) ----
    if (col == 0) {
        #pragma unroll
        for (int j = 0; j < 16; ++j) {
            mbB[rt][sh][kh][j] = best[j];
            mbI[rt][sh][kh][j] = bn[j];
        }
    }
    __syncthreads();

    // ---- wave 0 merges sample-halves (sh0 n < sh1 n: strict > keeps lowest)
    //      and writes all 64 rows, one per lane ----
    if (w == 0) {
        int rt_o = lane >> 5;
        int rr = lane & 31;
        int kh_o = (rr >> 2) & 1;
        int j_o = (rr & 3) | ((rr >> 3) << 2);
        float b0 = mbB[rt_o][0][kh_o][j_o];
        int i0 = mbI[rt_o][0][kh_o][j_o];
        float b1 = mbB[rt_o][1][kh_o][j_o];
        int i1 = mbI[rt_o][1][kh_o][j_o];
        int n = (b1 > b0) ? i1 : i0;
        int r = blockIdx.x * ROWSPB + rt_o * 32 + rr;
        int b = r >> 14, pos = (r >> 2) & (L - 1), ns = r & 3;
        out[(size_t)BB * C2 * L + ((size_t)b * NG + ns) * L + pos] = (float)n;
        float4 uu = p4[2 * n], vv = p4[2 * n + 1];
        float sv[8] = {uu.x, uu.y, uu.z, uu.w, vv.x, vv.y, vv.z, vv.w};
        #pragma unroll
        for (int g = 0; g < 8; ++g) {
            out[((size_t)b * C2 + g * NG + ns) * L + pos] = sv[g];
        }
    }
}

extern "C" void kernel_launch(void* const* d_in, const int* in_sizes, int n_in,
                              void* d_out, int out_size, void* d_ws, size_t ws_size,
                              hipStream_t stream) {
    const float* z = (const float*)d_in[0];
    const float* prior = (const float*)d_in[1];
    float* out = (float*)d_out;
    char* ws = (char*)d_ws;
    int bws = (ws_size >= (size_t)WS_B) ? 1 : 0;
    int aws = (ws_size >= (size_t)WS_A) ? 1 : 0;

    if (bws) {
        int nprep = 8 + (aws ? 256 : 0);
        hipLaunchKernelGGL(prep_kernel, dim3(nprep), dim3(256), 0, stream,
                           z, prior, ws);
    }
    hipLaunchKernelGGL(gqreg_main, dim3((BB * L * NG) / ROWSPB), dim3(TPB), 0, stream,
                       z, prior, out, (const char*)ws, bws, aws);
}